// Round 10
// baseline (1071.436 us; speedup 1.0000x reference)
//
#include <hip/hip_runtime.h>
#include <hip/hip_cooperative_groups.h>

namespace cg = cooperative_groups;

// Capsule dynamic routing — R16: single cooperative mega-kernel.
// u_i:(B,N,DI) f32, w:(1,N,NO,DI,DE) f32, bias:(N,NO,1) f32, r=3.
// R4/R8/R9 lesson: every weight-delivery restructure (asm-laundered vector,
// readlane payload, lambda/unrolled) triggers hipcc spill pathology
// (WRITE_SIZE 165-220MB); only the plain scalar-path R12 structure compiles
// clean (181.7us total). So routing/squash bodies below are EXACTLY R12.
// This round removes the other structural cost: 7 dispatches -> 1
// cooperative kernel (grid 256x640 = 1 blk/CU, == squash's 163840 threads),
// 6 kernel boundaries -> grid.sync() + device-scope fences (cross-XCD
// s_part/vsum visibility per G16). Runtime fallback to the proven
// multi-kernel path if cooperative launch is rejected.

#define B    256
#define N    1152
#define NO   10
#define DI   8
#define DE   16
#define NTILE   9
#define NTILES  128    // N / NTILE
#define BPT     2      // b per thread
#define BG      128    // b per block
#define BGS     2      // B / BG
#define THREADS 640    // 10 waves, o = wave id
#define GRID    (NTILES * BGS)   // 256 blocks = 1/CU

// ws layout (floats)
#define SP_OFF 0
#define SP_SZ  (NTILES * B * NO * DE)   // 5,242,880
#define VS_OFF (SP_OFF + SP_SZ)
#define VS_SZ  (B * NO * DE)            // 40,960
#define UT_OFF (VS_OFF + VS_SZ)
#define UT_SZ  (2 * N * B * 4)          // 2,359,296 (= B*N*DI)

// ---------------------------------------------------------------------------
// Routing body — EXACT R12 (proven clean codegen). id = block id (XCD-swizzled
// (tile,b-group) encoding), tid = thread id in block.
// ---------------------------------------------------------------------------
__device__ __forceinline__ void routing_body(
    const int id, const int tid,
    const float* __restrict__ u, const float* __restrict__ ut,
    const float* __restrict__ w, const float* __restrict__ bias,
    const float* __restrict__ vsum, float* __restrict__ s_part,
    const int has_v, const int use_ut)
{
    __shared__ float lgx[2][NO][BG];            // 10 KB double-buffered exchange
    const int lane = tid & 63;
    const int wv   = __builtin_amdgcn_readfirstlane(tid >> 6);  // 0..9, uniform
    const int o    = wv;                         // one output capsule per wave

    const int xcd  = id & 7;
    const int sg   = id >> 3;                    // 0..31
    const int g    = sg >> 4;                    // 0..1  (b-group)
    const int t    = ((sg & 15) << 3) | xcd;     // 0..127 (tile)
    const int n0   = t * NTILE;
    const int bb   = g * BG;                     // block's b base

    // Bias for this wave's o, all 9 n of the tile (scalar path, tiny).
    float bvs[NTILE];
#pragma unroll
    for (int i = 0; i < NTILE; ++i)
        bvs[i] = bias[(n0 + i) * NO + o];

    // vsum fragments for this thread's 2 b values — loop-invariant
    float4 vv[BPT][4];
#pragma unroll
    for (int bi = 0; bi < BPT; ++bi)
#pragma unroll
        for (int eq = 0; eq < 4; ++eq)
            vv[bi][eq] = make_float4(0.f, 0.f, 0.f, 0.f);
    if (has_v) {
#pragma unroll
        for (int bi = 0; bi < BPT; ++bi)
#pragma unroll
            for (int eq = 0; eq < 4; ++eq)
                vv[bi][eq] = *(const float4*)(vsum +
                    ((size_t)(bb + bi * 64 + lane) * NO + o) * DE + eq * 4);
    }

    float4 acc[BPT][4];
#pragma unroll
    for (int bi = 0; bi < BPT; ++bi)
#pragma unroll
        for (int eq = 0; eq < 4; ++eq)
            acc[bi][eq] = make_float4(0.f, 0.f, 0.f, 0.f);

    for (int i = 0; i < NTILE; ++i) {
        const int n = n0 + i;

        // u rows for this thread's 2 b — coalesced from ut, or legacy gather
        float ur[BPT][DI];
#pragma unroll
        for (int bi = 0; bi < BPT; ++bi) {
            const int b = bb + bi * 64 + lane;
            float4 u0, u1;
            if (use_ut) {
                const float* up = ut + ((size_t)(n * 2) * B + b) * 4;
                u0 = *(const float4*)up;
                u1 = *(const float4*)(up + B * 4);
            } else {
                const float* up = u + ((size_t)b * N + n) * DI;
                u0 = *(const float4*)up;
                u1 = *(const float4*)(up + 4);
            }
            ur[bi][0] = u0.x; ur[bi][1] = u0.y; ur[bi][2] = u0.z; ur[bi][3] = u0.w;
            ur[bi][4] = u1.x; ur[bi][5] = u1.y; ur[bi][6] = u1.z; ur[bi][7] = u1.w;
        }

        // u_ji for this wave's o, both b — weights wave-uniform (scalar path)
        const float* wp = w + ((size_t)n * NO + o) * (DI * DE);
        const float bv = bvs[i];
        float4 uji[BPT][4];
#pragma unroll
        for (int bi = 0; bi < BPT; ++bi)
#pragma unroll
            for (int eq = 0; eq < 4; ++eq)
                uji[bi][eq] = make_float4(bv, bv, bv, bv);
#pragma unroll
        for (int d = 0; d < DI; ++d) {
#pragma unroll
            for (int eq = 0; eq < 4; ++eq) {
                const float4 w4 = *(const float4*)(wp + d * DE + eq * 4);
#pragma unroll
                for (int bi = 0; bi < BPT; ++bi) {
                    uji[bi][eq].x += ur[bi][d] * w4.x;
                    uji[bi][eq].y += ur[bi][d] * w4.y;
                    uji[bi][eq].z += ur[bi][d] * w4.z;
                    uji[bi][eq].w += ur[bi][d] * w4.w;
                }
            }
        }

        float c[BPT];
        if (has_v) {
            const int pb = i & 1;
#pragma unroll
            for (int bi = 0; bi < BPT; ++bi) {
                float lg = 0.f;
#pragma unroll
                for (int eq = 0; eq < 4; ++eq)
                    lg += uji[bi][eq].x * vv[bi][eq].x + uji[bi][eq].y * vv[bi][eq].y
                        + uji[bi][eq].z * vv[bi][eq].z + uji[bi][eq].w * vv[bi][eq].w;
                lgx[pb][o][bi * 64 + lane] = lg;
            }
            __syncthreads();
#pragma unroll
            for (int bi = 0; bi < BPT; ++bi) {
                float l[NO];
#pragma unroll
                for (int oo = 0; oo < NO; ++oo) l[oo] = lgx[pb][oo][bi * 64 + lane];
                float m = l[0];
#pragma unroll
                for (int oo = 1; oo < NO; ++oo) m = fmaxf(m, l[oo]);
                float sum = 0.f;
#pragma unroll
                for (int oo = 0; oo < NO; ++oo) { l[oo] = __expf(l[oo] - m); sum += l[oo]; }
                c[bi] = l[o] / sum;
            }
            // no second barrier: buffer pb next written at i+2, separated by
            // the barrier at i+1.
        } else {
            c[0] = 0.1f; c[1] = 0.1f;   // softmax of zeros
        }

#pragma unroll
        for (int bi = 0; bi < BPT; ++bi)
#pragma unroll
            for (int eq = 0; eq < 4; ++eq) {
                acc[bi][eq].x += c[bi] * uji[bi][eq].x;
                acc[bi][eq].y += c[bi] * uji[bi][eq].y;
                acc[bi][eq].z += c[bi] * uji[bi][eq].z;
                acc[bi][eq].w += c[bi] * uji[bi][eq].w;
            }
    }

    // s_part[tile][b][o][e]
#pragma unroll
    for (int bi = 0; bi < BPT; ++bi) {
        float* sp = s_part + (((size_t)t * B + bb + bi * 64 + lane) * NO + o) * DE;
#pragma unroll
        for (int eq = 0; eq < 4; ++eq)
            *(float4*)(sp + eq * 4) = acc[bi][eq];
    }
}

// ---------------------------------------------------------------------------
// Squash body — EXACT R12 (NTILES=128: 4 quarters x 32 tiles).
// t0 in [0, 4*B*NO*DE). write_out/write_vsum control the epilogue.
// ---------------------------------------------------------------------------
__device__ __forceinline__ void squash_body(
    const int t0,
    const float* __restrict__ s_part, float* __restrict__ vsum,
    float* __restrict__ out,
    const int accum, const int write_out, const int write_vsum)
{
    const int q  = t0 & 3;
    const int g  = t0 >> 2;

    float s = 0.f;
    const float* sp = s_part + (size_t)(q * 32) * (B * NO * DE) + g;
#pragma unroll 8
    for (int i = 0; i < 32; ++i)
        s += sp[(size_t)i * (B * NO * DE)];
    s += __shfl_xor(s, 1);
    s += __shfl_xor(s, 2);        // full tile sum, all q lanes

    float nsq = s * s;
#pragma unroll
    for (int msk = 4; msk <= 32; msk <<= 1) nsq += __shfl_xor(nsq, msk);
    const float nrm   = sqrtf(nsq);
    const float scale = nrm / (1.f + nsq);
    const float val   = s * scale;

    if (q == 0) {
        if (write_out)  out[g]  = val;
        if (write_vsum) vsum[g] = accum ? (vsum[g] + val) : val;
    }
}

// ---------------------------------------------------------------------------
// Fused cooperative kernel: [transpose] -> 3 x (routing -> squash).
// Grid 256 x 640 = 163840 threads = exactly squash's 4*B*NO*DE decomposition.
// ---------------------------------------------------------------------------
__global__ __launch_bounds__(THREADS, 2)
void capsule_fused(const float* __restrict__ u, float* __restrict__ ut,
                   const float* __restrict__ w, const float* __restrict__ bias,
                   float* __restrict__ vsum, float* __restrict__ s_part,
                   float* __restrict__ out, const int use_ut)
{
    cg::grid_group grid = cg::this_grid();
    const int id  = blockIdx.x;
    const int tid = threadIdx.x;

    // phase 0: one-time u transpose into ut (grid-strided; coalesced writes)
    if (use_ut) {
        for (int idx = id * THREADS + tid; idx < N * B; idx += GRID * THREADS) {
            const int n = idx >> 8;              // B = 256
            const int b = idx & (B - 1);
            const float* up = u + ((size_t)b * N + n) * DI;
            const float4 a0 = *(const float4*)up;
            const float4 a1 = *(const float4*)(up + 4);
            *(float4*)(ut + ((size_t)(n * 2 + 0) * B + b) * 4) = a0;
            *(float4*)(ut + ((size_t)(n * 2 + 1) * B + b) * 4) = a1;
        }
        __threadfence();
        grid.sync();
        __threadfence();
    }

    for (int it = 0; it < 3; ++it) {
        routing_body(id, tid, u, ut, w, bias, vsum, s_part, it > 0, use_ut);
        __threadfence();          // release s_part to device scope (cross-XCD)
        grid.sync();
        __threadfence();          // acquire before reading s_part

        squash_body(id * THREADS + tid, s_part, vsum, out,
                    /*accum=*/it > 0, /*write_out=*/it == 2,
                    /*write_vsum=*/it < 2);
        if (it < 2) {
            __threadfence();      // release vsum
            grid.sync();
            __threadfence();      // acquire before routing reads vsum
        }
    }
}

// ---------------------------------------------------------------------------
// Standalone kernels — fallback path (proven R12 multi-launch).
// ---------------------------------------------------------------------------
__global__ __launch_bounds__(256)
void transpose_kernel(const float* __restrict__ u, float* __restrict__ ut) {
    const int lane = threadIdx.x & 63;
    const int wv   = threadIdx.x >> 6;           // 0..3 -> n offset
    const int n    = blockIdx.x * 4 + wv;
    const int b    = blockIdx.y * 64 + lane;
    const float* up = u + ((size_t)b * N + n) * DI;
    const float4 a0 = *(const float4*)up;
    const float4 a1 = *(const float4*)(up + 4);
    *(float4*)(ut + ((size_t)(n * 2 + 0) * B + b) * 4) = a0;
    *(float4*)(ut + ((size_t)(n * 2 + 1) * B + b) * 4) = a1;
}

__global__ __launch_bounds__(THREADS, 2)
void routing_kernel(const float* __restrict__ u,
                    const float* __restrict__ ut,
                    const float* __restrict__ w,
                    const float* __restrict__ bias,
                    const float* __restrict__ vsum,
                    float* __restrict__ s_part,
                    const int has_v,
                    const int use_ut) {
    routing_body(blockIdx.x, threadIdx.x, u, ut, w, bias, vsum, s_part,
                 has_v, use_ut);
}

__global__ __launch_bounds__(256)
void squash_kernel(const float* __restrict__ s_part,
                   float* __restrict__ vsum,
                   float* __restrict__ out,
                   const int accum) {
    squash_body(blockIdx.x * 256 + threadIdx.x, s_part, vsum, out,
                accum, /*write_out=*/1, /*write_vsum=*/1);
}

extern "C" void kernel_launch(void* const* d_in, const int* in_sizes, int n_in,
                              void* d_out, int out_size, void* d_ws, size_t ws_size,
                              hipStream_t stream) {
    const float* u    = (const float*)d_in[0];
    const float* w    = (const float*)d_in[1];   // (N,NO,DI,DE)
    const float* bias = (const float*)d_in[2];   // (N,NO)
    // d_in[3] = r, static 3

    float* wsf    = (float*)d_ws;
    float* s_part = wsf + SP_OFF;
    float* vsum   = wsf + VS_OFF;
    float* ut     = wsf + UT_OFF;
    float* out    = (float*)d_out;

    const int use_ut = (ws_size >= (size_t)(SP_SZ + VS_SZ + UT_SZ) * sizeof(float));

    // Preferred: single cooperative kernel (1 block/CU, co-resident).
    void* args[] = {(void*)&u, (void*)&ut, (void*)&w, (void*)&bias,
                    (void*)&vsum, (void*)&s_part, (void*)&out, (void*)&use_ut};
    hipError_t err = hipLaunchCooperativeKernel(
        (const void*)capsule_fused, dim3(GRID), dim3(THREADS), args, 0, stream);

    if (err != hipSuccess) {
        // Fallback: proven R12 multi-launch sequence.
        if (use_ut)
            transpose_kernel<<<dim3(N / 4, B / 64), 256, 0, stream>>>(u, ut);
        for (int it = 0; it < 3; ++it) {
            routing_kernel<<<GRID, THREADS, 0, stream>>>(
                u, ut, w, bias, vsum, s_part, it > 0, use_ut);
            squash_kernel<<<(4 * B * NO * DE) / 256, 256, 0, stream>>>(
                s_part, vsum, out, it > 0);
        }
    }
}

// Round 11
// 201.554 us; speedup vs baseline: 5.3159x; 5.3159x over previous
//
#include <hip/hip_runtime.h>

// Capsule dynamic routing — R17: materialize u_ji (fp32) once, stream it in
// iterations 1-2. u_i:(B,N,DI) f32, w:(1,N,NO,DI,DE) f32, bias:(N,NO,1), r=3.
// Evidence chain:
//   - Routing's wall = per-CU unique weight-line miss service: 9n x 5120B =
//     720 lines x ~130cy = ~39us/launch, invariant across scalar (R2/R12),
//     LDS (R3), vector-broadcast (R5) delivery; register-resident variants
//     spill (R4/R8/R9). Cooperative fusion 5x worse (R10).
//   - R10's fillBufferAligned resets write exactly 256 MiB -> ws_size ~256MB,
//     so u_ji fp32 (189MB) fits: phase1 = PROVEN R12 it0 body + fire-and-
//     forget uji stores; phase2/3 stream uji coalesced (no scalar path, no
//     weight wall, L3-resident). fp32 -> bitwise-equivalent math, absmax
//     unchanged. Host guard: ws too small -> exact R12 fallback (181.7us).

#define B    256
#define N    1152
#define NO   10
#define DI   8
#define DE   16
#define NTILE   9
#define NTILES  128    // N / NTILE
#define BPT     2      // b per thread
#define BG      128    // b per block
#define BGS     2      // B / BG
#define THREADS 640    // 10 waves, o = wave id
#define GRID    (NTILES * BGS)   // 256 blocks = 1/CU

// ws layout (floats)
#define SP_OFF 0
#define SP_SZ  (NTILES * B * NO * DE)   // 5,242,880
#define VS_OFF (SP_OFF + SP_SZ)
#define VS_SZ  (B * NO * DE)            // 40,960
#define UT_OFF (VS_OFF + VS_SZ)
#define UT_SZ  (2 * N * B * 4)          // 2,359,296 (= B*N*DI)
#define UJ_OFF (UT_OFF + UT_SZ)
#define UJ_SZ  ((size_t)N * NO * 4 * B * 4)   // 47,185,920 (189 MB fp32)

// ---------------------------------------------------------------------------
// One-time transpose: u (B,N,8) -> ut[((n*2+h)*B + b)*4 + j] = u[b][n][h*4+j]
// ---------------------------------------------------------------------------
__global__ __launch_bounds__(256)
void transpose_kernel(const float* __restrict__ u, float* __restrict__ ut) {
    const int lane = threadIdx.x & 63;
    const int wv   = threadIdx.x >> 6;           // 0..3 -> n offset
    const int n    = blockIdx.x * 4 + wv;
    const int b    = blockIdx.y * 64 + lane;
    const float* up = u + ((size_t)b * N + n) * DI;
    const float4 a0 = *(const float4*)up;
    const float4 a1 = *(const float4*)(up + 4);
    *(float4*)(ut + ((size_t)(n * 2 + 0) * B + b) * 4) = a0;
    *(float4*)(ut + ((size_t)(n * 2 + 1) * B + b) * 4) = a1;
}

// Block id decode, shared by all routing-shaped kernels:
// id = (t&7) + 8*((t>>3) + 16*g)  -> same-tile blocks on one XCD.
#define DECODE_ID()                                        \
    const int xcd  = id & 7;                               \
    const int sg   = id >> 3;                              \
    const int g    = sg >> 4;                              \
    const int t    = ((sg & 15) << 3) | xcd;               \
    const int n0   = t * NTILE;                            \
    const int bb   = g * BG;

// ---------------------------------------------------------------------------
// Phase 1 (it=0): EXACT R12 routing body with has_v=0, plus uji stores.
// uj layout: uj[((n*NO + o)*4 + eq)*B + b][0..3]  (per-instr 64x16B coalesced)
// ---------------------------------------------------------------------------
__global__ __launch_bounds__(THREADS, 3)
void phase1_kernel(const float* __restrict__ ut,
                   const float* __restrict__ w,
                   const float* __restrict__ bias,
                   float* __restrict__ s_part,
                   float* __restrict__ uj) {
    const int tid  = threadIdx.x;
    const int lane = tid & 63;
    const int wv   = __builtin_amdgcn_readfirstlane(tid >> 6);
    const int o    = wv;
    const int id   = blockIdx.x;
    DECODE_ID();

    float bvs[NTILE];
#pragma unroll
    for (int i = 0; i < NTILE; ++i)
        bvs[i] = bias[(n0 + i) * NO + o];

    float4 acc[BPT][4];
#pragma unroll
    for (int bi = 0; bi < BPT; ++bi)
#pragma unroll
        for (int eq = 0; eq < 4; ++eq)
            acc[bi][eq] = make_float4(0.f, 0.f, 0.f, 0.f);

    for (int i = 0; i < NTILE; ++i) {
        const int n = n0 + i;

        float ur[BPT][DI];
#pragma unroll
        for (int bi = 0; bi < BPT; ++bi) {
            const int b = bb + bi * 64 + lane;
            const float* up = ut + ((size_t)(n * 2) * B + b) * 4;
            const float4 u0 = *(const float4*)up;
            const float4 u1 = *(const float4*)(up + B * 4);
            ur[bi][0] = u0.x; ur[bi][1] = u0.y; ur[bi][2] = u0.z; ur[bi][3] = u0.w;
            ur[bi][4] = u1.x; ur[bi][5] = u1.y; ur[bi][6] = u1.z; ur[bi][7] = u1.w;
        }

        const float* wp = w + ((size_t)n * NO + o) * (DI * DE);
        const float bv = bvs[i];
        float4 uji[BPT][4];
#pragma unroll
        for (int bi = 0; bi < BPT; ++bi)
#pragma unroll
            for (int eq = 0; eq < 4; ++eq)
                uji[bi][eq] = make_float4(bv, bv, bv, bv);
#pragma unroll
        for (int d = 0; d < DI; ++d) {
#pragma unroll
            for (int eq = 0; eq < 4; ++eq) {
                const float4 w4 = *(const float4*)(wp + d * DE + eq * 4);
#pragma unroll
                for (int bi = 0; bi < BPT; ++bi) {
                    uji[bi][eq].x += ur[bi][d] * w4.x;
                    uji[bi][eq].y += ur[bi][d] * w4.y;
                    uji[bi][eq].z += ur[bi][d] * w4.z;
                    uji[bi][eq].w += ur[bi][d] * w4.w;
                }
            }
        }

        // store uji (fire-and-forget, coalesced) + accumulate c=0.1
#pragma unroll
        for (int bi = 0; bi < BPT; ++bi) {
            const int b = bb + bi * 64 + lane;
#pragma unroll
            for (int eq = 0; eq < 4; ++eq) {
                *(float4*)(uj + ((((size_t)n * NO + o) * 4 + eq) * B + b) * 4)
                    = uji[bi][eq];
                acc[bi][eq].x += 0.1f * uji[bi][eq].x;
                acc[bi][eq].y += 0.1f * uji[bi][eq].y;
                acc[bi][eq].z += 0.1f * uji[bi][eq].z;
                acc[bi][eq].w += 0.1f * uji[bi][eq].w;
            }
        }
    }

#pragma unroll
    for (int bi = 0; bi < BPT; ++bi) {
        float* sp = s_part + (((size_t)t * B + bb + bi * 64 + lane) * NO + o) * DE;
#pragma unroll
        for (int eq = 0; eq < 4; ++eq)
            *(float4*)(sp + eq * 4) = acc[bi][eq];
    }
}

// ---------------------------------------------------------------------------
// Phase 2 (it=1,2): stream uji, logits + softmax + weighted acc. No weights,
// no scalar path — pure coalesced vector loads.
// ---------------------------------------------------------------------------
__global__ __launch_bounds__(THREADS, 3)
void phase2_kernel(const float* __restrict__ uj,
                   const float* __restrict__ vsum,
                   float* __restrict__ s_part) {
    __shared__ float lgx[2][NO][BG];
    const int tid  = threadIdx.x;
    const int lane = tid & 63;
    const int wv   = __builtin_amdgcn_readfirstlane(tid >> 6);
    const int o    = wv;
    const int id   = blockIdx.x;
    DECODE_ID();

    float4 vv[BPT][4];
#pragma unroll
    for (int bi = 0; bi < BPT; ++bi)
#pragma unroll
        for (int eq = 0; eq < 4; ++eq)
            vv[bi][eq] = *(const float4*)(vsum +
                ((size_t)(bb + bi * 64 + lane) * NO + o) * DE + eq * 4);

    float4 acc[BPT][4];
#pragma unroll
    for (int bi = 0; bi < BPT; ++bi)
#pragma unroll
        for (int eq = 0; eq < 4; ++eq)
            acc[bi][eq] = make_float4(0.f, 0.f, 0.f, 0.f);

    for (int i = 0; i < NTILE; ++i) {
        const int n = n0 + i;

        float4 uji[BPT][4];
#pragma unroll
        for (int bi = 0; bi < BPT; ++bi) {
            const int b = bb + bi * 64 + lane;
#pragma unroll
            for (int eq = 0; eq < 4; ++eq)
                uji[bi][eq] = *(const float4*)(uj +
                    ((((size_t)n * NO + o) * 4 + eq) * B + b) * 4);
        }

        const int pb = i & 1;
#pragma unroll
        for (int bi = 0; bi < BPT; ++bi) {
            float lg = 0.f;
#pragma unroll
            for (int eq = 0; eq < 4; ++eq)
                lg += uji[bi][eq].x * vv[bi][eq].x + uji[bi][eq].y * vv[bi][eq].y
                    + uji[bi][eq].z * vv[bi][eq].z + uji[bi][eq].w * vv[bi][eq].w;
            lgx[pb][o][bi * 64 + lane] = lg;
        }
        __syncthreads();
        float c[BPT];
#pragma unroll
        for (int bi = 0; bi < BPT; ++bi) {
            float l[NO];
#pragma unroll
            for (int oo = 0; oo < NO; ++oo) l[oo] = lgx[pb][oo][bi * 64 + lane];
            float m = l[0];
#pragma unroll
            for (int oo = 1; oo < NO; ++oo) m = fmaxf(m, l[oo]);
            float sum = 0.f;
#pragma unroll
            for (int oo = 0; oo < NO; ++oo) { l[oo] = __expf(l[oo] - m); sum += l[oo]; }
            c[bi] = l[o] / sum;
        }
        // buffer pb next written at i+2, separated by i+1's barrier.

#pragma unroll
        for (int bi = 0; bi < BPT; ++bi)
#pragma unroll
            for (int eq = 0; eq < 4; ++eq) {
                acc[bi][eq].x += c[bi] * uji[bi][eq].x;
                acc[bi][eq].y += c[bi] * uji[bi][eq].y;
                acc[bi][eq].z += c[bi] * uji[bi][eq].z;
                acc[bi][eq].w += c[bi] * uji[bi][eq].w;
            }
    }

#pragma unroll
    for (int bi = 0; bi < BPT; ++bi) {
        float* sp = s_part + (((size_t)t * B + bb + bi * 64 + lane) * NO + o) * DE;
#pragma unroll
        for (int eq = 0; eq < 4; ++eq)
            *(float4*)(sp + eq * 4) = acc[bi][eq];
    }
}

// ---------------------------------------------------------------------------
// Fallback routing (EXACT R12) for small-ws path.
// ---------------------------------------------------------------------------
__global__ __launch_bounds__(THREADS, 3)
void routing_kernel(const float* __restrict__ u,
                    const float* __restrict__ ut,
                    const float* __restrict__ w,
                    const float* __restrict__ bias,
                    const float* __restrict__ vsum,
                    float* __restrict__ s_part,
                    const int has_v,
                    const int use_ut) {
    __shared__ float lgx[2][NO][BG];
    const int tid  = threadIdx.x;
    const int lane = tid & 63;
    const int wv   = __builtin_amdgcn_readfirstlane(tid >> 6);
    const int o    = wv;
    const int id   = blockIdx.x;
    DECODE_ID();

    float bvs[NTILE];
#pragma unroll
    for (int i = 0; i < NTILE; ++i)
        bvs[i] = bias[(n0 + i) * NO + o];

    float4 vv[BPT][4];
#pragma unroll
    for (int bi = 0; bi < BPT; ++bi)
#pragma unroll
        for (int eq = 0; eq < 4; ++eq)
            vv[bi][eq] = make_float4(0.f, 0.f, 0.f, 0.f);
    if (has_v) {
#pragma unroll
        for (int bi = 0; bi < BPT; ++bi)
#pragma unroll
            for (int eq = 0; eq < 4; ++eq)
                vv[bi][eq] = *(const float4*)(vsum +
                    ((size_t)(bb + bi * 64 + lane) * NO + o) * DE + eq * 4);
    }

    float4 acc[BPT][4];
#pragma unroll
    for (int bi = 0; bi < BPT; ++bi)
#pragma unroll
        for (int eq = 0; eq < 4; ++eq)
            acc[bi][eq] = make_float4(0.f, 0.f, 0.f, 0.f);

    for (int i = 0; i < NTILE; ++i) {
        const int n = n0 + i;
        float ur[BPT][DI];
#pragma unroll
        for (int bi = 0; bi < BPT; ++bi) {
            const int b = bb + bi * 64 + lane;
            float4 u0, u1;
            if (use_ut) {
                const float* up = ut + ((size_t)(n * 2) * B + b) * 4;
                u0 = *(const float4*)up;
                u1 = *(const float4*)(up + B * 4);
            } else {
                const float* up = u + ((size_t)b * N + n) * DI;
                u0 = *(const float4*)up;
                u1 = *(const float4*)(up + 4);
            }
            ur[bi][0] = u0.x; ur[bi][1] = u0.y; ur[bi][2] = u0.z; ur[bi][3] = u0.w;
            ur[bi][4] = u1.x; ur[bi][5] = u1.y; ur[bi][6] = u1.z; ur[bi][7] = u1.w;
        }

        const float* wp = w + ((size_t)n * NO + o) * (DI * DE);
        const float bv = bvs[i];
        float4 uji[BPT][4];
#pragma unroll
        for (int bi = 0; bi < BPT; ++bi)
#pragma unroll
            for (int eq = 0; eq < 4; ++eq)
                uji[bi][eq] = make_float4(bv, bv, bv, bv);
#pragma unroll
        for (int d = 0; d < DI; ++d) {
#pragma unroll
            for (int eq = 0; eq < 4; ++eq) {
                const float4 w4 = *(const float4*)(wp + d * DE + eq * 4);
#pragma unroll
                for (int bi = 0; bi < BPT; ++bi) {
                    uji[bi][eq].x += ur[bi][d] * w4.x;
                    uji[bi][eq].y += ur[bi][d] * w4.y;
                    uji[bi][eq].z += ur[bi][d] * w4.z;
                    uji[bi][eq].w += ur[bi][d] * w4.w;
                }
            }
        }

        float c[BPT];
        if (has_v) {
            const int pb = i & 1;
#pragma unroll
            for (int bi = 0; bi < BPT; ++bi) {
                float lg = 0.f;
#pragma unroll
                for (int eq = 0; eq < 4; ++eq)
                    lg += uji[bi][eq].x * vv[bi][eq].x + uji[bi][eq].y * vv[bi][eq].y
                        + uji[bi][eq].z * vv[bi][eq].z + uji[bi][eq].w * vv[bi][eq].w;
                lgx[pb][o][bi * 64 + lane] = lg;
            }
            __syncthreads();
#pragma unroll
            for (int bi = 0; bi < BPT; ++bi) {
                float l[NO];
#pragma unroll
                for (int oo = 0; oo < NO; ++oo) l[oo] = lgx[pb][oo][bi * 64 + lane];
                float m = l[0];
#pragma unroll
                for (int oo = 1; oo < NO; ++oo) m = fmaxf(m, l[oo]);
                float sum = 0.f;
#pragma unroll
                for (int oo = 0; oo < NO; ++oo) { l[oo] = __expf(l[oo] - m); sum += l[oo]; }
                c[bi] = l[o] / sum;
            }
        } else {
            c[0] = 0.1f; c[1] = 0.1f;
        }

#pragma unroll
        for (int bi = 0; bi < BPT; ++bi)
#pragma unroll
            for (int eq = 0; eq < 4; ++eq) {
                acc[bi][eq].x += c[bi] * uji[bi][eq].x;
                acc[bi][eq].y += c[bi] * uji[bi][eq].y;
                acc[bi][eq].z += c[bi] * uji[bi][eq].z;
                acc[bi][eq].w += c[bi] * uji[bi][eq].w;
            }
    }

#pragma unroll
    for (int bi = 0; bi < BPT; ++bi) {
        float* sp = s_part + (((size_t)t * B + bb + bi * 64 + lane) * NO + o) * DE;
#pragma unroll
        for (int eq = 0; eq < 4; ++eq)
            *(float4*)(sp + eq * 4) = acc[bi][eq];
    }
}

// ---------------------------------------------------------------------------
// Squash (unchanged, NTILES=128): s = sum s_part; v = ||s||/(1+||s||^2)*s.
// ---------------------------------------------------------------------------
__global__ __launch_bounds__(256)
void squash_kernel(const float* __restrict__ s_part,
                   float* __restrict__ vsum,
                   float* __restrict__ out,
                   const int accum) {
    const int t0 = blockIdx.x * 256 + threadIdx.x;
    const int q  = t0 & 3;
    const int g  = t0 >> 2;

    float s = 0.f;
    const float* sp = s_part + (size_t)(q * 32) * (B * NO * DE) + g;
#pragma unroll 8
    for (int i = 0; i < 32; ++i)
        s += sp[(size_t)i * (B * NO * DE)];
    s += __shfl_xor(s, 1);
    s += __shfl_xor(s, 2);

    float nsq = s * s;
#pragma unroll
    for (int msk = 4; msk <= 32; msk <<= 1) nsq += __shfl_xor(nsq, msk);
    const float nrm   = sqrtf(nsq);
    const float scale = nrm / (1.f + nsq);
    const float val   = s * scale;

    if (q == 0) {
        out[g]  = val;
        vsum[g] = accum ? (vsum[g] + val) : val;
    }
}

extern "C" void kernel_launch(void* const* d_in, const int* in_sizes, int n_in,
                              void* d_out, int out_size, void* d_ws, size_t ws_size,
                              hipStream_t stream) {
    const float* u    = (const float*)d_in[0];
    const float* w    = (const float*)d_in[1];
    const float* bias = (const float*)d_in[2];
    // d_in[3] = r, static 3

    float* wsf    = (float*)d_ws;
    float* s_part = wsf + SP_OFF;
    float* vsum   = wsf + VS_OFF;
    float* ut     = wsf + UT_OFF;
    float* uj     = wsf + UJ_OFF;
    float* out    = (float*)d_out;

    const size_t need_uj = ((size_t)UJ_OFF + UJ_SZ) * sizeof(float);
    const int use_uj = (ws_size >= need_uj);
    const int use_ut = (ws_size >= (size_t)(SP_SZ + VS_SZ + UT_SZ) * sizeof(float));

    if (use_uj) {
        transpose_kernel<<<dim3(N / 4, B / 64), 256, 0, stream>>>(u, ut);
        // it = 0: compute + materialize u_ji, c = 0.1
        phase1_kernel<<<GRID, THREADS, 0, stream>>>(ut, w, bias, s_part, uj);
        squash_kernel<<<(4 * B * NO * DE) / 256, 256, 0, stream>>>(
            s_part, vsum, out, 0);
        // it = 1, 2: stream u_ji
        for (int it = 1; it < 3; ++it) {
            phase2_kernel<<<GRID, THREADS, 0, stream>>>(uj, vsum, s_part);
            squash_kernel<<<(4 * B * NO * DE) / 256, 256, 0, stream>>>(
                s_part, vsum, out, 1);
        }
    } else {
        // proven R12 fallback
        if (use_ut)
            transpose_kernel<<<dim3(N / 4, B / 64), 256, 0, stream>>>(u, ut);
        for (int it = 0; it < 3; ++it) {
            routing_kernel<<<GRID, THREADS, 0, stream>>>(
                u, ut, w, bias, vsum, s_part, it > 0, use_ut);
            squash_kernel<<<(4 * B * NO * DE) / 256, 256, 0, stream>>>(
                s_part, vsum, out, it > 0);
        }
    }
}

// Round 12
// 181.121 us; speedup vs baseline: 5.9156x; 1.1128x over previous
//
#include <hip/hip_runtime.h>

// Capsule dynamic routing — R18: R12 structure + LDS-staged weights.
// u_i:(B,N,DI) f32, w:(1,N,NO,DI,DE) f32, bias:(N,NO,1) f32, r=3.
// Identity: logits_r = u_ji . vsum (u_ji includes bias so bias folds in).
// Evidence chain (R1-R11):
//   - Scalar-path weight wall: K$ miss->L2 ~200cy, ~2 MSHRs -> ~130cy/line
//     serialized; 9n x 80 lines = 720 lines/CU/launch = ~39us. Invariant
//     under delivery mechanism; register-resident variants spill (R4/R8/R9);
//     coop fusion 5x worse (R10); fp32 materialization BW-bound (R11).
//   - Vector+LDS at the RIGHT geometry untested: R3's 56us was 2.25 blk/CU
//     with replicated staging + imbalance. At R12 geometry (1 blk/CU, BPT=2,
//     9n): staging 46KB coalesced (~1us, deep-MSHR pipelined) + LDS broadcast
//     10 waves x 32 ds_read_b128 x 9 steps x 12cy = 14.4us/CU -> ~20us/launch.
// R18 = R12 byte-for-byte except: weights staged to LDS once per block
// (one extra barrier), inner loop reads wt[] (uniform-addr b128 broadcast).

#define B    256
#define N    1152
#define NO   10
#define DI   8
#define DE   16
#define NTILE   9
#define NTILES  128    // N / NTILE
#define BPT     2      // b per thread
#define BG      128    // b per block
#define BGS     2      // B / BG
#define THREADS 640    // 10 waves, o = wave id
#define GRID    (NTILES * BGS)   // 256 blocks = 1/CU

// ws layout (floats)
#define SP_OFF 0
#define SP_SZ  (NTILES * B * NO * DE)   // 5,242,880
#define VS_OFF (SP_OFF + SP_SZ)
#define VS_SZ  (B * NO * DE)            // 40,960
#define UT_OFF (VS_OFF + VS_SZ)
#define UT_SZ  (2 * N * B * 4)          // 2,359,296 (= B*N*DI)

// ---------------------------------------------------------------------------
// One-time transpose: u (B,N,8) -> ut[((n*2+h)*B + b)*4 + j] = u[b][n][h*4+j]
// ---------------------------------------------------------------------------
__global__ __launch_bounds__(256)
void transpose_kernel(const float* __restrict__ u, float* __restrict__ ut) {
    const int lane = threadIdx.x & 63;
    const int wv   = threadIdx.x >> 6;           // 0..3 -> n offset
    const int n    = blockIdx.x * 4 + wv;
    const int b    = blockIdx.y * 64 + lane;
    const float* up = u + ((size_t)b * N + n) * DI;
    const float4 a0 = *(const float4*)up;
    const float4 a1 = *(const float4*)(up + 4);
    *(float4*)(ut + ((size_t)(n * 2 + 0) * B + b) * 4) = a0;
    *(float4*)(ut + ((size_t)(n * 2 + 1) * B + b) * 4) = a1;
}

// ---------------------------------------------------------------------------
// Routing pass. Grid: 256 blocks x 640 threads (10 waves). 1 block/CU.
// Block id encodes (tile t, b-group g) with same-tile blocks on one XCD:
//   id = (t&7) + 8*((t>>3) + 16*g)
// ---------------------------------------------------------------------------
__global__ __launch_bounds__(THREADS, 3)
void routing_kernel(const float* __restrict__ u,
                    const float* __restrict__ ut,
                    const float* __restrict__ w,
                    const float* __restrict__ bias,
                    const float* __restrict__ vsum,
                    float* __restrict__ s_part,
                    const int has_v,
                    const int use_ut) {
    __shared__ float wt[NTILE * NO * DI * DE];  // 46,080 B weight tile
    __shared__ float lgx[2][NO][BG];            // 10 KB double-buffered exchange
    const int tid  = threadIdx.x;
    const int lane = tid & 63;
    const int wv   = __builtin_amdgcn_readfirstlane(tid >> 6);  // 0..9, uniform
    const int o    = wv;                         // one output capsule per wave

    const int id   = blockIdx.x;
    const int xcd  = id & 7;
    const int sg   = id >> 3;                    // 0..31
    const int g    = sg >> 4;                    // 0..1  (b-group)
    const int t    = ((sg & 15) << 3) | xcd;     // 0..127 (tile)
    const int n0   = t * NTILE;
    const int bb   = g * BG;                     // block's b base

    // Stage the tile's weights: 11520 floats = 2880 float4, coalesced vector
    // loads (deep-MSHR pipelined; the 720 lines come in ~overlapped, not
    // serialized like the scalar K$ path).
    {
        const float4* wg = (const float4*)(w + (size_t)n0 * NO * DI * DE);
        float4* wl = (float4*)wt;
#pragma unroll
        for (int c = 0; c < 5; ++c) {
            const int idx = c * THREADS + tid;
            if (idx < (NTILE * NO * DI * DE) / 4)
                wl[idx] = wg[idx];
        }
    }

    // Bias for this wave's o, all 9 n of the tile (scalar path, tiny).
    float bvs[NTILE];
#pragma unroll
    for (int i = 0; i < NTILE; ++i)
        bvs[i] = bias[(n0 + i) * NO + o];

    // vsum fragments for this thread's 2 b values — loop-invariant
    float4 vv[BPT][4];
#pragma unroll
    for (int bi = 0; bi < BPT; ++bi)
#pragma unroll
        for (int eq = 0; eq < 4; ++eq)
            vv[bi][eq] = make_float4(0.f, 0.f, 0.f, 0.f);
    if (has_v) {
#pragma unroll
        for (int bi = 0; bi < BPT; ++bi)
#pragma unroll
            for (int eq = 0; eq < 4; ++eq)
                vv[bi][eq] = *(const float4*)(vsum +
                    ((size_t)(bb + bi * 64 + lane) * NO + o) * DE + eq * 4);
    }

    float4 acc[BPT][4];
#pragma unroll
    for (int bi = 0; bi < BPT; ++bi)
#pragma unroll
        for (int eq = 0; eq < 4; ++eq)
            acc[bi][eq] = make_float4(0.f, 0.f, 0.f, 0.f);

    __syncthreads();   // weights staged

    for (int i = 0; i < NTILE; ++i) {
        const int n = n0 + i;

        // u rows for this thread's 2 b — coalesced from ut, or legacy gather
        float ur[BPT][DI];
#pragma unroll
        for (int bi = 0; bi < BPT; ++bi) {
            const int b = bb + bi * 64 + lane;
            float4 u0, u1;
            if (use_ut) {
                const float* up = ut + ((size_t)(n * 2) * B + b) * 4;
                u0 = *(const float4*)up;
                u1 = *(const float4*)(up + B * 4);
            } else {
                const float* up = u + ((size_t)b * N + n) * DI;
                u0 = *(const float4*)up;
                u1 = *(const float4*)(up + 4);
            }
            ur[bi][0] = u0.x; ur[bi][1] = u0.y; ur[bi][2] = u0.z; ur[bi][3] = u0.w;
            ur[bi][4] = u1.x; ur[bi][5] = u1.y; ur[bi][6] = u1.z; ur[bi][7] = u1.w;
        }

        // u_ji for this wave's o, both b — weights from LDS, uniform-address
        // ds_read_b128 broadcasts (base + imm offsets 0..496B, conflict-free).
        const float* wrow = wt + (i * NO + o) * (DI * DE);
        const float bv = bvs[i];
        float4 uji[BPT][4];
#pragma unroll
        for (int bi = 0; bi < BPT; ++bi)
#pragma unroll
            for (int eq = 0; eq < 4; ++eq)
                uji[bi][eq] = make_float4(bv, bv, bv, bv);
#pragma unroll
        for (int d = 0; d < DI; ++d) {
#pragma unroll
            for (int eq = 0; eq < 4; ++eq) {
                const float4 w4 = *(const float4*)(wrow + d * DE + eq * 4);
#pragma unroll
                for (int bi = 0; bi < BPT; ++bi) {
                    uji[bi][eq].x += ur[bi][d] * w4.x;
                    uji[bi][eq].y += ur[bi][d] * w4.y;
                    uji[bi][eq].z += ur[bi][d] * w4.z;
                    uji[bi][eq].w += ur[bi][d] * w4.w;
                }
            }
        }

        float c[BPT];
        if (has_v) {
            const int pb = i & 1;
            // logits: full-e dot in-thread, exchange via LDS for the softmax
#pragma unroll
            for (int bi = 0; bi < BPT; ++bi) {
                float lg = 0.f;
#pragma unroll
                for (int eq = 0; eq < 4; ++eq)
                    lg += uji[bi][eq].x * vv[bi][eq].x + uji[bi][eq].y * vv[bi][eq].y
                        + uji[bi][eq].z * vv[bi][eq].z + uji[bi][eq].w * vv[bi][eq].w;
                lgx[pb][o][bi * 64 + lane] = lg;
            }
            __syncthreads();
#pragma unroll
            for (int bi = 0; bi < BPT; ++bi) {
                float l[NO];
#pragma unroll
                for (int oo = 0; oo < NO; ++oo) l[oo] = lgx[pb][oo][bi * 64 + lane];
                float m = l[0];
#pragma unroll
                for (int oo = 1; oo < NO; ++oo) m = fmaxf(m, l[oo]);
                float sum = 0.f;
#pragma unroll
                for (int oo = 0; oo < NO; ++oo) { l[oo] = __expf(l[oo] - m); sum += l[oo]; }
                c[bi] = l[o] / sum;
            }
            // no second barrier: buffer pb next written at i+2, separated by
            // the barrier at i+1.
        } else {
            c[0] = 0.1f; c[1] = 0.1f;   // softmax of zeros
        }

#pragma unroll
        for (int bi = 0; bi < BPT; ++bi)
#pragma unroll
            for (int eq = 0; eq < 4; ++eq) {
                acc[bi][eq].x += c[bi] * uji[bi][eq].x;
                acc[bi][eq].y += c[bi] * uji[bi][eq].y;
                acc[bi][eq].z += c[bi] * uji[bi][eq].z;
                acc[bi][eq].w += c[bi] * uji[bi][eq].w;
            }
    }

    // s_part[tile][b][o][e] — same layout squash expects
#pragma unroll
    for (int bi = 0; bi < BPT; ++bi) {
        float* sp = s_part + (((size_t)t * B + bb + bi * 64 + lane) * NO + o) * DE;
#pragma unroll
        for (int eq = 0; eq < 4; ++eq)
            *(float4*)(sp + eq * 4) = acc[bi][eq];
    }
}

// ---------------------------------------------------------------------------
// Squash: s = sum_tiles s_part; v = ||s||/(1+||s||^2)*s; out = v; vsum += v.
// 4 threads/element, 32 tiles each (NTILES=128).
// ---------------------------------------------------------------------------
__global__ __launch_bounds__(256)
void squash_kernel(const float* __restrict__ s_part,
                   float* __restrict__ vsum,
                   float* __restrict__ out,
                   const int accum) {
    const int t0 = blockIdx.x * 256 + threadIdx.x;   // < 4*40960
    const int q  = t0 & 3;
    const int g  = t0 >> 2;

    float s = 0.f;
    const float* sp = s_part + (size_t)(q * 32) * (B * NO * DE) + g;
#pragma unroll 8
    for (int i = 0; i < 32; ++i)
        s += sp[(size_t)i * (B * NO * DE)];
    s += __shfl_xor(s, 1);
    s += __shfl_xor(s, 2);        // full tile sum, all q lanes

    float nsq = s * s;
#pragma unroll
    for (int msk = 4; msk <= 32; msk <<= 1) nsq += __shfl_xor(nsq, msk);
    const float nrm   = sqrtf(nsq);
    const float scale = nrm / (1.f + nsq);
    const float val   = s * scale;

    if (q == 0) {
        out[g]  = val;                               // (B,NO,DE)
        vsum[g] = accum ? (vsum[g] + val) : val;
    }
}

extern "C" void kernel_launch(void* const* d_in, const int* in_sizes, int n_in,
                              void* d_out, int out_size, void* d_ws, size_t ws_size,
                              hipStream_t stream) {
    const float* u    = (const float*)d_in[0];
    const float* w    = (const float*)d_in[1];   // (N,NO,DI,DE)
    const float* bias = (const float*)d_in[2];   // (N,NO)
    // d_in[3] = r, static 3

    float* wsf    = (float*)d_ws;
    float* s_part = wsf + SP_OFF;
    float* vsum   = wsf + VS_OFF;
    float* ut     = wsf + UT_OFF;
    float* out    = (float*)d_out;

    const int use_ut = (ws_size >= (size_t)(SP_SZ + VS_SZ + UT_SZ) * sizeof(float));

    if (use_ut)
        transpose_kernel<<<dim3(N / 4, B / 64), 256, 0, stream>>>(u, ut);

    for (int it = 0; it < 3; ++it) {
        routing_kernel<<<GRID, THREADS, 0, stream>>>(
            u, ut, w, bias, vsum, s_part, it > 0, use_ut);
        squash_kernel<<<(4 * B * NO * DE) / 256, 256, 0, stream>>>(
            s_part, vsum, out, it > 0);
    }
}